// Round 10
// baseline (31.503 us; speedup 1.0000x reference)
//
#include <hip/hip_runtime.h>

// TransientGenerator — LDS-resident templates.
// Theory: R4's FETCH_SIZE=1157MB (inputs=0.44MB) proves ~10x HBM read
// amplification: the 41MB output stream evicts template lines from the 4MB
// XCD L2s before cross-block reuse, so every (chunk,transient) window touch
// refetches from L3/HBM (~150-250MB -> the 25us wall). Fix: stage ALL
// templates (20*1600*4 = 128000B) in LDS once per block; template reads
// never touch the cache hierarchy again.
// 1 block (1024 thr, 16 waves, ~131KB LDS) per (batch, quarter-track) = 256
// blocks = 1/CU. One barrier; waves then sweep 1024-sample sub-chunks
// independently (register-ballot interval, uniform per-row skip, NT stores).

constexpr int SR    = 16000;   // SAMPLE_RATE
constexpr int TL    = 1600;    // TRANSIENT_SAMPLES
constexpr int MAXT  = 256;     // MAX_TRANSIENTS
constexpr int NTR   = 20;      // N_TRANSIENTS (reference constant; guarded at launch)
constexpr int NTHR  = 1024;    // threads per block (16 waves)
constexpr int SUB   = 1024;    // samples per wave sub-chunk (64 lanes * 16)
constexpr int KPL   = 16;      // samples per lane per sub-chunk
constexpr int QUART = 4;       // blocks per batch

__global__ __launch_bounds__(NTHR)
void transient_lds(const float* __restrict__ timings,   // [B,T]
                   const int*   __restrict__ ids,       // [B,T]
                   const float* __restrict__ gains,     // [B,T]
                   const float* __restrict__ templates, // [n_tr,TL]
                   float*       __restrict__ out,       // [B,A]
                   int T, int n_tr, int A)
{
    __shared__ float s_tmpl[NTR * TL];   // 128000 B — all templates
    __shared__ int2  s_m[MAXT];          // (ts<<8)|id , gain bits (0 if invalid)

    const int b    = blockIdx.x / QUART;
    const int q    = blockIdx.x - b * QUART;
    const int tid  = (int)threadIdx.x;
    const int lane = tid & 63;
    const int wave = tid >> 6;           // 0..15

    // quarter-track range [q0, qend)
    const int qlen = (A + QUART - 1) / QUART;
    const int q0   = q * qlen;
    const int qend = min(A, q0 + qlen);

    // ---- stage all templates: coalesced float4 global loads -> LDS ----
    {
        const float4* src = reinterpret_cast<const float4*>(templates);
        float4*       dst = reinterpret_cast<float4*>(s_tmpl);
        const int nv = (n_tr * TL) / 4;                 // 8000 for 20x1600
        for (int i = tid; i < nv; i += NTHR) dst[i] = src[i];
    }
    // ---- stage meta (threads 0..T-1) ----
    if (tid < T) {
        const float tm = timings[(size_t)b * T + tid];
        const float g  = gains  [(size_t)b * T + tid];
        const int   id = ids    [(size_t)b * T + tid];
        const int   ts = (int)floorf(tm * (float)SR);   // matches jnp.floor(t*SR) fp32
        const bool ok  = (g > 0.0f) & (id < n_tr) & (ts < A);
        const int tsc  = min(max(ts, 0), A);            // clamp preserves sorted order
        const int idc  = min(max(id, 0), n_tr - 1);
        s_m[tid] = make_int2((tsc << 8) | idc, ok ? __float_as_int(g) : 0);
    }
    __syncthreads();                                    // the only barrier

    // each wave caches the 256 sorted start-times in 4 regs/lane
    int tsr[4];
#pragma unroll
    for (int qq = 0; qq < 4; ++qq) tsr[qq] = s_m[qq * 64 + lane].x >> 8;

    const int nsub = (qend - q0 + SUB - 1) / SUB;

    for (int sc = wave; sc < nsub; sc += NTHR / 64) {   // waves independent, no barriers
        const int sub0 = q0 + sc * SUB;

        // overlap interval [lo,hi] via 4 in-register ballots (sorted ts)
        int lo = T, hi = -1;
#pragma unroll
        for (int qq = 0; qq < 4; ++qq) {
            const bool ov = (tsr[qq] < sub0 + SUB) & (tsr[qq] + TL > sub0);
            const unsigned long long m = __ballot(ov);
            if (m) {
                lo = min(lo, qq * 64 + (int)__builtin_ctzll(m));
                hi = max(hi, qq * 64 + 63 - (int)__builtin_clzll(m));
            }
        }

        float acc[KPL];
#pragma unroll
        for (int k = 0; k < KPL; ++k) acc[k] = 0.0f;

        for (int j = lo; j <= hi; ++j) {
            const int2 mj  = s_m[j];                    // broadcast ds_read_b64
            const int  mx  = __builtin_amdgcn_readfirstlane(mj.x);
            const int  mgb = __builtin_amdgcn_readfirstlane(mj.y);
            if (mgb == 0) continue;                     // uniform: invalid transient
            const float g   = __int_as_float(mgb);
            const int   ts  = mx >> 8;
            const int   rb  = (mx & 255) * TL;          // row base in LDS
            const int   dlt = sub0 - ts;                // in (-SUB, TL)
#pragma unroll
            for (int k = 0; k < KPL; ++k) {
                const int offk = dlt + k * 64;          // uniform row offset
                if (offk <= -64 || offk >= TL) continue;   // uniform row skip
                const int o  = offk + lane;
                const int oc = min(max(o, 0), TL - 1);
                const float v = s_tmpl[rb + oc];        // lane-consecutive, conflict-free
                acc[k] = fmaf(((unsigned)o < (unsigned)TL) ? g : 0.0f, v, acc[k]);
            }
        }

        float* ob = out + (size_t)b * A + sub0 + lane;
#pragma unroll
        for (int k = 0; k < KPL; ++k) {
            if (sub0 + k * 64 + lane < qend)
                __builtin_nontemporal_store(acc[k], &ob[k * 64]);
        }
    }
}

// ---- fallback (proven R7 guarded kernel) if templates don't fit LDS ----
constexpr int FNT   = 256;
constexpr int FCH   = 1024;
__global__ __launch_bounds__(FNT)
void transient_gather_guard(const float* __restrict__ timings, const int* __restrict__ ids,
                            const float* __restrict__ gains, const float* __restrict__ templates,
                            float* __restrict__ out, int T, int n_tr, int A)
{
    __shared__ int2               s_m[MAXT];
    __shared__ unsigned long long s_mask[FNT / 64];
    const int b = blockIdx.y, chunk0 = blockIdx.x * FCH, tid = (int)threadIdx.x;
    {
        const float tm = timings[(size_t)b * T + tid];
        const float g  = gains  [(size_t)b * T + tid];
        const int   id = ids    [(size_t)b * T + tid];
        const int   ts = (int)floorf(tm * (float)SR);
        const bool ok  = (g > 0.0f) & (id < n_tr) & (ts < A);
        const int tsc  = min(max(ts, 0), A);
        const int idc  = min(max(id, 0), n_tr - 1);
        s_m[tid] = make_int2((tsc << 8) | idc, ok ? __float_as_int(g) : 0);
        const bool ov = (tsc < chunk0 + FCH) && (tsc + TL > chunk0);
        const unsigned long long mball = __ballot(ov);
        if ((tid & 63) == 0) s_mask[tid >> 6] = mball;
    }
    __syncthreads();
    int lo = T, hi = -1;
#pragma unroll
    for (int w = 0; w < FNT / 64; ++w) {
        const unsigned long long mw = s_mask[w];
        if (mw) {
            lo = min(lo, w * 64 + (int)__builtin_ctzll(mw));
            hi = max(hi, w * 64 + 63 - (int)__builtin_clzll(mw));
        }
    }
    float acc[4] = {0.f, 0.f, 0.f, 0.f};
    const int off_base = chunk0 + tid;
    for (int j = lo; j <= hi; ++j) {
        const int2 m = s_m[j];
        const int ts = m.x >> 8;
        const float g = __int_as_float(m.y);
        const float* __restrict__ row = templates + (size_t)(m.x & 255) * TL;
        const int off0 = off_base - ts;
#pragma unroll
        for (int k = 0; k < 4; ++k) {
            const int o = off0 + k * FNT;
            if ((unsigned)o < (unsigned)TL) acc[k] += g * row[o];
        }
    }
    float* ob = out + (size_t)b * A + off_base;
#pragma unroll
    for (int k = 0; k < 4; ++k)
        if (off_base + k * FNT < A) __builtin_nontemporal_store(acc[k], &ob[k * FNT]);
}

extern "C" void kernel_launch(void* const* d_in, const int* in_sizes, int n_in,
                              void* d_out, int out_size, void* d_ws, size_t ws_size,
                              hipStream_t stream) {
    const float* timings   = (const float*)d_in[0];
    const int*   ids       = (const int*)  d_in[1];
    const float* gains     = (const float*)d_in[2];
    const float* templates = (const float*)d_in[3];
    float*       out       = (float*)d_out;

    const int T    = MAXT;                 // reference MAX_TRANSIENTS
    const int B    = in_sizes[0] / T;
    const int n_tr = in_sizes[3] / TL;     // templates are [n_tr, TL]
    const int A    = out_size / B;         // audio_length

    if (n_tr <= NTR && (n_tr * TL) % 4 == 0) {
        dim3 grid(B * QUART), block(NTHR);
        transient_lds<<<grid, block, 0, stream>>>(timings, ids, gains, templates, out,
                                                  T, n_tr, A);
    } else {
        dim3 grid((A + FCH - 1) / FCH, B), block(FNT);
        transient_gather_guard<<<grid, block, 0, stream>>>(timings, ids, gains, templates,
                                                           out, T, n_tr, A);
    }
}

// Round 11
// 30.100 us; speedup vs baseline: 1.0466x; 1.0466x over previous
//
#include <hip/hip_runtime.h>

// TransientGenerator — LDS-resident PADDED templates (R10 repaired).
// All 20 templates live in LDS as [64 zeros | 1600 | 64 zeros] rows (138 KB),
// so the inner loop is pure {ds_read_b32 + fmaf} with immediate offsets:
// no bounds checks, no clamps (uniform row-skip guarantees in-row offsets).
// 1 block (1024 thr) per (batch, quarter-track); one barrier; waves sweep
// 1024-sample sub-chunks independently with register-ballot intervals.
// Goal: template reads never touch the (write-thrashed) L2/HBM path.

constexpr int SR    = 16000;   // SAMPLE_RATE
constexpr int TL    = 1600;    // TRANSIENT_SAMPLES
constexpr int MAXT  = 256;     // MAX_TRANSIENTS
constexpr int NTR   = 20;      // N_TRANSIENTS (guarded at launch)
constexpr int RPAD  = 64;      // row pad each side (covers offk in (-64,TL))
constexpr int ROWL  = RPAD + TL + RPAD;   // 1728 floats per LDS row
constexpr int NTHR  = 1024;    // 16 waves
constexpr int SUB   = 1024;    // samples per wave sub-chunk
constexpr int KPL   = 16;      // samples per lane (SUB/64)
constexpr int QUART = 4;       // blocks per batch

__global__ __launch_bounds__(NTHR)
void transient_lds(const float* __restrict__ timings,   // [B,T]
                   const int*   __restrict__ ids,       // [B,T]
                   const float* __restrict__ gains,     // [B,T]
                   const float* __restrict__ templates, // [n_tr,TL]
                   float*       __restrict__ out,       // [B,A]
                   int T, int n_tr, int A)
{
    __shared__ float s_tmpl[NTR * ROWL];  // 138240 B, zero-padded rows
    __shared__ int2  s_m[MAXT];           // (ts<<8)|id , gain bits (0 if invalid)

    const int b    = blockIdx.x / QUART;
    const int q    = blockIdx.x - b * QUART;
    const int tid  = (int)threadIdx.x;
    const int lane = tid & 63;
    const int wave = tid >> 6;            // 0..15

    const int qlen = (A + QUART - 1) / QUART;
    const int q0   = q * qlen;
    const int qend = min(A, q0 + qlen);

    // ---- stage padded templates (pad zones = 0) ----
    for (int i = tid; i < n_tr * ROWL; i += NTHR) {
        const int r = i / ROWL;
        const int c = i - r * ROWL - RPAD;
        s_tmpl[i] = ((unsigned)c < (unsigned)TL) ? templates[(size_t)r * TL + c] : 0.0f;
    }
    // ---- stage meta (threads 0..T-1) ----
    if (tid < T) {
        const float tm = timings[(size_t)b * T + tid];
        const float g  = gains  [(size_t)b * T + tid];
        const int   id = ids    [(size_t)b * T + tid];
        const int   ts = (int)floorf(tm * (float)SR);   // matches jnp.floor(t*SR) fp32
        const bool ok  = (g > 0.0f) & (id < n_tr) & (ts < A);
        const int tsc  = min(max(ts, 0), A);            // clamp preserves sorted order
        const int idc  = min(max(id, 0), n_tr - 1);
        s_m[tid] = make_int2((tsc << 8) | idc, ok ? __float_as_int(g) : 0);
    }
    __syncthreads();                                    // the only barrier

    // per-wave register cache of the 256 sorted start-times (for ballots)
    int tsr[4];
#pragma unroll
    for (int qq = 0; qq < 4; ++qq) tsr[qq] = s_m[qq * 64 + lane].x >> 8;

    const int nsub = (qend - q0 + SUB - 1) / SUB;

    for (int sc = wave; sc < nsub; sc += NTHR / 64) {   // waves independent
        const int sub0 = q0 + sc * SUB;

        int lo = T, hi = -1;
#pragma unroll
        for (int qq = 0; qq < 4; ++qq) {
            const bool ov = (tsr[qq] < sub0 + SUB) & (tsr[qq] + TL > sub0);
            const unsigned long long m = __ballot(ov);
            if (m) {
                lo = min(lo, qq * 64 + (int)__builtin_ctzll(m));
                hi = max(hi, qq * 64 + 63 - (int)__builtin_clzll(m));
            }
        }

        float acc[KPL];
#pragma unroll
        for (int k = 0; k < KPL; ++k) acc[k] = 0.0f;

        for (int j = lo; j <= hi; ++j) {
            const int2 mj  = s_m[j];                    // broadcast ds_read_b64
            const int  mx  = __builtin_amdgcn_readfirstlane(mj.x);
            const int  mgb = __builtin_amdgcn_readfirstlane(mj.y);
            if (mgb == 0) continue;                     // uniform: invalid transient
            const float g   = __int_as_float(mgb);
            const int   ts  = mx >> 8;
            const int   dlt = sub0 - ts;                // in (-SUB, TL)
            // base index: all reachable offsets lie inside the padded row
            const float* __restrict__ p =
                s_tmpl + (mx & 255) * ROWL + RPAD + dlt + lane;

            if (dlt >= 0 && dlt + SUB <= TL) {
                // interior: straight-line 16 x {ds_read + fma}, imm offsets
#pragma unroll
                for (int k = 0; k < KPL; ++k)
                    acc[k] = fmaf(g, p[k * 64], acc[k]);
            } else {
                // edge: uniform per-row skip, still no per-lane masks
#pragma unroll
                for (int k = 0; k < KPL; ++k) {
                    const int offk = dlt + k * 64;
                    if (offk > -64 && offk < TL)
                        acc[k] = fmaf(g, p[k * 64], acc[k]);
                }
            }
        }

        float* ob = out + (size_t)b * A + sub0 + lane;
#pragma unroll
        for (int k = 0; k < KPL; ++k) {
            if (sub0 + k * 64 + lane < qend)
                __builtin_nontemporal_store(acc[k], &ob[k * 64]);
        }
    }
}

// ---- fallback (proven R7 kernel) if templates don't fit the LDS layout ----
constexpr int FNT = 256;
constexpr int FCH = 1024;
__global__ __launch_bounds__(FNT)
void transient_gather_guard(const float* __restrict__ timings, const int* __restrict__ ids,
                            const float* __restrict__ gains, const float* __restrict__ templates,
                            float* __restrict__ out, int T, int n_tr, int A)
{
    __shared__ int2               s_m[MAXT];
    __shared__ unsigned long long s_mask[FNT / 64];
    const int b = blockIdx.y, chunk0 = blockIdx.x * FCH, tid = (int)threadIdx.x;
    {
        const float tm = timings[(size_t)b * T + tid];
        const float g  = gains  [(size_t)b * T + tid];
        const int   id = ids    [(size_t)b * T + tid];
        const int   ts = (int)floorf(tm * (float)SR);
        const bool ok  = (g > 0.0f) & (id < n_tr) & (ts < A);
        const int tsc  = min(max(ts, 0), A);
        const int idc  = min(max(id, 0), n_tr - 1);
        s_m[tid] = make_int2((tsc << 8) | idc, ok ? __float_as_int(g) : 0);
        const bool ov = (tsc < chunk0 + FCH) && (tsc + TL > chunk0);
        const unsigned long long mball = __ballot(ov);
        if ((tid & 63) == 0) s_mask[tid >> 6] = mball;
    }
    __syncthreads();
    int lo = T, hi = -1;
#pragma unroll
    for (int w = 0; w < FNT / 64; ++w) {
        const unsigned long long mw = s_mask[w];
        if (mw) {
            lo = min(lo, w * 64 + (int)__builtin_ctzll(mw));
            hi = max(hi, w * 64 + 63 - (int)__builtin_clzll(mw));
        }
    }
    float acc[4] = {0.f, 0.f, 0.f, 0.f};
    const int off_base = chunk0 + tid;
    for (int j = lo; j <= hi; ++j) {
        const int2 m = s_m[j];
        const int ts = m.x >> 8;
        const float g = __int_as_float(m.y);
        const float* __restrict__ row = templates + (size_t)(m.x & 255) * TL;
        const int off0 = off_base - ts;
#pragma unroll
        for (int k = 0; k < 4; ++k) {
            const int o = off0 + k * FNT;
            if ((unsigned)o < (unsigned)TL) acc[k] += g * row[o];
        }
    }
    float* ob = out + (size_t)b * A + off_base;
#pragma unroll
    for (int k = 0; k < 4; ++k)
        if (off_base + k * FNT < A) __builtin_nontemporal_store(acc[k], &ob[k * FNT]);
}

extern "C" void kernel_launch(void* const* d_in, const int* in_sizes, int n_in,
                              void* d_out, int out_size, void* d_ws, size_t ws_size,
                              hipStream_t stream) {
    const float* timings   = (const float*)d_in[0];
    const int*   ids       = (const int*)  d_in[1];
    const float* gains     = (const float*)d_in[2];
    const float* templates = (const float*)d_in[3];
    float*       out       = (float*)d_out;

    const int T    = MAXT;                 // reference MAX_TRANSIENTS
    const int B    = in_sizes[0] / T;
    const int n_tr = in_sizes[3] / TL;     // templates are [n_tr, TL]
    const int A    = out_size / B;         // audio_length

    if (n_tr <= NTR) {
        dim3 grid(B * QUART), block(NTHR);
        transient_lds<<<grid, block, 0, stream>>>(timings, ids, gains, templates, out,
                                                  T, n_tr, A);
    } else {
        dim3 grid((A + FCH - 1) / FCH, B), block(FNT);
        transient_gather_guard<<<grid, block, 0, stream>>>(timings, ids, gains, templates,
                                                           out, T, n_tr, A);
    }
}

// Round 12
// 26.023 us; speedup vs baseline: 1.2106x; 1.1567x over previous
//
#include <hip/hip_runtime.h>

// TransientGenerator — best measured kernel (R7 form, 24.98 us).
// Gather with stride-64 lane mapping: thread tid owns samples
// chunk0 + tid + k*256, so template loads are lane-consecutive.
// Overlap interval via one ballot round (sorted ts => interval).
// Uniform meta scalarized with readfirstlane; NT stores keep the 41 MB
// output stream from thrashing L2 (+5%, the only reproducible win).
// Session conclusion: time = ~18 us fixed per-replay overhead + ~7 us
// write stream; 11 structural variants land 25-31 us, floor ~25 us.

constexpr int SR    = 16000;  // SAMPLE_RATE
constexpr int TL    = 1600;   // TRANSIENT_SAMPLES
constexpr int MAXT  = 256;    // MAX_TRANSIENTS (== blockDim)
constexpr int NTHR  = 256;
constexpr int CHUNK = 1024;   // NTHR * 4 samples per block

__global__ __launch_bounds__(NTHR)
void transient_gather(const float* __restrict__ timings,   // [B,T]
                      const int*   __restrict__ ids,       // [B,T]
                      const float* __restrict__ gains,     // [B,T]
                      const float* __restrict__ templates, // [n_tr,TL]
                      float*       __restrict__ out,       // [B,A]
                      int T, int n_tr, int A)
{
    __shared__ int2               s_m[MAXT];   // (ts<<8)|id (clamped), gain bits (0 if invalid)
    __shared__ unsigned long long s_mask[NTHR / 64];

    const int b      = blockIdx.y;
    const int chunk0 = blockIdx.x * CHUNK;
    const int tid    = (int)threadIdx.x;

    {   // stage transient j = tid (T == NTHR); ballot the overlap interval
        const float tm = timings[(size_t)b * T + tid];
        const float g  = gains  [(size_t)b * T + tid];
        const int   id = ids    [(size_t)b * T + tid];
        const int   ts = (int)floorf(tm * (float)SR);   // matches jnp.floor(t*SR) in fp32
        const bool ok  = (g > 0.0f) & (id < n_tr) & (ts < A);
        const int tsc  = min(max(ts, 0), A);            // clamp preserves sorted order
        const int idc  = min(max(id, 0), n_tr - 1);
        s_m[tid] = make_int2((tsc << 8) | idc, ok ? __float_as_int(g) : 0);
        const bool ov = (tsc < chunk0 + CHUNK) && (tsc + TL > chunk0);
        const unsigned long long mball = __ballot(ov);
        if ((tid & 63) == 0) s_mask[tid >> 6] = mball;
    }
    __syncthreads();

    int lo = T, hi = -1;
#pragma unroll
    for (int w = 0; w < NTHR / 64; ++w) {
        const unsigned long long mw = s_mask[w];
        if (mw) {
            lo = min(lo, w * 64 + (int)__builtin_ctzll(mw));
            hi = max(hi, w * 64 + 63 - (int)__builtin_clzll(mw));
        }
    }

    float acc[4] = {0.f, 0.f, 0.f, 0.f};
    const int off_base = chunk0 + tid;

    for (int j = lo; j <= hi; ++j) {                    // known trip count, no break
        const int2 mj  = s_m[j];                        // broadcast ds_read_b64
        const int  mx  = __builtin_amdgcn_readfirstlane(mj.x);   // uniform -> SGPR
        const int  mgb = __builtin_amdgcn_readfirstlane(mj.y);
        if (mgb == 0) continue;                         // uniform skip (invalid)
        const float g  = __int_as_float(mgb);
        const int   ts = mx >> 8;
        const float* __restrict__ row = templates + (size_t)(mx & 255) * TL;
        const int off0 = off_base - ts;
#pragma unroll
        for (int k = 0; k < 4; ++k) {
            const int o = off0 + k * NTHR;
            if ((unsigned)o < (unsigned)TL)             // exec-masked, lane-consecutive
                acc[k] += g * row[o];
        }
    }

    // NT stores: stream the 41 MB output past L2 so templates stay resident.
    float* ob = out + (size_t)b * A + off_base;
#pragma unroll
    for (int k = 0; k < 4; ++k) {
        if (off_base + k * NTHR < A)
            __builtin_nontemporal_store(acc[k], &ob[k * NTHR]);
    }
}

extern "C" void kernel_launch(void* const* d_in, const int* in_sizes, int n_in,
                              void* d_out, int out_size, void* d_ws, size_t ws_size,
                              hipStream_t stream) {
    const float* timings   = (const float*)d_in[0];
    const int*   ids       = (const int*)  d_in[1];
    const float* gains     = (const float*)d_in[2];
    const float* templates = (const float*)d_in[3];
    float*       out       = (float*)d_out;

    const int T    = MAXT;                 // reference MAX_TRANSIENTS
    const int B    = in_sizes[0] / T;
    const int n_tr = in_sizes[3] / TL;     // templates are [n_tr, TL]
    const int A    = out_size / B;         // audio_length

    dim3 grid((A + CHUNK - 1) / CHUNK, B), block(NTHR);
    transient_gather<<<grid, block, 0, stream>>>(timings, ids, gains, templates, out,
                                                 T, n_tr, A);
}